// Round 2
// baseline (499.049 us; speedup 1.0000x reference)
//
#include <hip/hip_runtime.h>

#define HID 128
#define OUTC 32

// ---- K0: Wcomb = W2 @ W_fc  [128,32]; bcomb = b2 @ W_fc + b_fc [32] ----
__global__ void k_wcomb(const float* __restrict__ W2, const float* __restrict__ Wfc,
                        const float* __restrict__ b2, const float* __restrict__ bfc,
                        float* __restrict__ Wc, float* __restrict__ bc) {
    int t = blockIdx.x * blockDim.x + threadIdx.x;
    if (t < HID * OUTC) {
        int k = t / OUTC, o = t % OUTC;
        float acc = 0.f;
        #pragma unroll 8
        for (int j = 0; j < HID; ++j) acc += W2[k * HID + j] * Wfc[j * OUTC + o];
        Wc[t] = acc;
    }
    if (t < OUTC) {
        float acc = bfc[t];
        #pragma unroll 8
        for (int j = 0; j < HID; ++j) acc += b2[j] * Wfc[j * OUTC + t];
        bc[t] = acc;
    }
}

// ---- K1: in-degree histogram over dst (self-loop added later) ----
__global__ void k_deg(const int* __restrict__ dst, int E, float* __restrict__ deg) {
    int e = blockIdx.x * blockDim.x + threadIdx.x;
    if (e < E) atomicAdd(&deg[dst[e]], 1.0f);
}

// ---- K2: dinv = rsqrt(deg + 1)  (the +1 is the self-loop) ----
__global__ void k_dinv(float* __restrict__ deg, int N) {
    int i = blockIdx.x * blockDim.x + threadIdx.x;
    if (i < N) deg[i] = rsqrtf(deg[i] + 1.0f);
}

// ---- K3: scalar layer-1 scatter: s[dst] += x[src]*dinv[src]*dinv[dst] ----
__global__ void k_s_scatter(const int* __restrict__ ei, int E,
                            const float* __restrict__ x, const float* __restrict__ dinv,
                            float* __restrict__ s) {
    int e = blockIdx.x * blockDim.x + threadIdx.x;
    if (e < E) {
        int u = ei[e];
        int v = ei[E + e];
        atomicAdd(&s[v], x[u] * dinv[u] * dinv[v]);
    }
}

// ---- K4: P[i,:] = relu(stot[i]*W1 + b1) @ Wcomb   [N,32] ----
// stot = s[i] + x[i]*dinv[i]^2  (layer-1 self-loop folded in)
__global__ void k_P(const float* __restrict__ x, const float* __restrict__ s,
                    const float* __restrict__ dinv, const float* __restrict__ W1,
                    const float* __restrict__ b1, const float* __restrict__ Wc,
                    float* __restrict__ P, int N) {
    int t = blockIdx.x * blockDim.x + threadIdx.x;
    int i = t / OUTC, o = t % OUTC;
    if (i < N) {
        float di = dinv[i];
        float stot = s[i] + x[i] * di * di;
        float acc = 0.f;
        #pragma unroll 8
        for (int j = 0; j < HID; ++j) {
            float h = stot * W1[j] + b1[j];
            h = h > 0.f ? h : 0.f;
            acc += h * Wc[j * OUTC + o];
        }
        P[t] = acc;
    }
}

// ---- K5: init out with bias + layer-2 self-loop term ----
__global__ void k_init_out(const float* __restrict__ P, const float* __restrict__ dinv,
                           const float* __restrict__ bc, float* __restrict__ out, int N) {
    int t = blockIdx.x * blockDim.x + threadIdx.x;
    if (t < N * OUTC) {
        int i = t / OUTC, o = t % OUTC;
        float di = dinv[i];
        out[t] = bc[o] + P[t] * di * di;
    }
}

// ---- K6: layer-2 edge scatter (32 lanes per edge): out[dst,:] += P[src,:]*norm ----
__global__ void k_edge_scatter(const int* __restrict__ ei, int E,
                               const float* __restrict__ dinv, const float* __restrict__ P,
                               float* __restrict__ out) {
    int t = blockIdx.x * blockDim.x + threadIdx.x;
    int e = t >> 5;           // OUTC == 32
    int o = t & 31;
    if (e < E) {
        int u = ei[e];
        int v = ei[E + e];
        float norm = dinv[u] * dinv[v];
        atomicAdd(&out[v * OUTC + o], P[u * OUTC + o] * norm);
    }
}

extern "C" void kernel_launch(void* const* d_in, const int* in_sizes, int n_in,
                              void* d_out, int out_size, void* d_ws, size_t ws_size,
                              hipStream_t stream) {
    const float* x   = (const float*)d_in[0];
    const int*   ei  = (const int*)d_in[1];   // [2,E] int32: row0=src, row1=dst
    const float* W1  = (const float*)d_in[2];
    const float* b1  = (const float*)d_in[3];
    const float* W2  = (const float*)d_in[4];
    const float* b2  = (const float*)d_in[5];
    const float* Wfc = (const float*)d_in[6];
    const float* bfc = (const float*)d_in[7];
    float* out = (float*)d_out;

    const int N = in_sizes[0];
    const int E = in_sizes[1] / 2;

    // workspace layout (floats): 2N + N*32 + 128*32 + 32  ~= 13.7 MB
    float* ws   = (float*)d_ws;
    float* dinv = ws;                    // N   (deg, then dinv in place)
    float* s    = ws + N;                // N
    float* P    = ws + 2 * N;            // N*32
    float* Wc   = P + (size_t)N * OUTC;  // 128*32
    float* bc   = Wc + HID * OUTC;       // 32

    // zero deg + s
    hipMemsetAsync(ws, 0, (size_t)2 * N * sizeof(float), stream);

    k_wcomb<<<(HID * OUTC + 255) / 256, 256, 0, stream>>>(W2, Wfc, b2, bfc, Wc, bc);
    k_deg<<<(E + 255) / 256, 256, 0, stream>>>(ei + E, E, dinv);
    k_dinv<<<(N + 255) / 256, 256, 0, stream>>>(dinv, N);
    k_s_scatter<<<(E + 255) / 256, 256, 0, stream>>>(ei, E, x, dinv, s);
    k_P<<<(N * OUTC + 255) / 256, 256, 0, stream>>>(x, s, dinv, W1, b1, Wc, P, N);
    k_init_out<<<(N * OUTC + 255) / 256, 256, 0, stream>>>(P, dinv, bc, out, N);
    {
        long long threads = (long long)E * OUTC;
        int blocks = (int)((threads + 255) / 256);
        k_edge_scatter<<<blocks, 256, 0, stream>>>(ei, E, dinv, P, out);
    }
}

// Round 3
// 442.527 us; speedup vs baseline: 1.1277x; 1.1277x over previous
//
#include <hip/hip_runtime.h>

#define HID 128
#define OUTC 32
#define SCAN_T 256
#define SCAN_B 1024   // elements per scan block (SCAN_T * 4)

// ---- K0: Wcomb = W2 @ W_fc  [128,32]; bcomb = b2 @ W_fc + b_fc [32] ----
__global__ void k_wcomb(const float* __restrict__ W2, const float* __restrict__ Wfc,
                        const float* __restrict__ b2, const float* __restrict__ bfc,
                        float* __restrict__ Wc, float* __restrict__ bc) {
    int t = blockIdx.x * blockDim.x + threadIdx.x;
    if (t < HID * OUTC) {
        int k = t / OUTC, o = t % OUTC;
        float acc = 0.f;
        #pragma unroll 8
        for (int j = 0; j < HID; ++j) acc += W2[k * HID + j] * Wfc[j * OUTC + o];
        Wc[t] = acc;
    }
    if (t < OUTC) {
        float acc = bfc[t];
        #pragma unroll 8
        for (int j = 0; j < HID; ++j) acc += b2[j] * Wfc[j * OUTC + t];
        bc[t] = acc;
    }
}

// ---- K1: int in-degree histogram over dst ----
__global__ void k_deg(const int* __restrict__ dst, int E, int* __restrict__ deg) {
    int e = blockIdx.x * blockDim.x + threadIdx.x;
    if (e < E) atomicAdd(&deg[dst[e]], 1);
}

// ---- K2: dinv = rsqrt(deg+1); xd = x*dinv ----
__global__ void k_dinv(const int* __restrict__ deg, const float* __restrict__ x,
                       float* __restrict__ dinv, float* __restrict__ xd, int N) {
    int i = blockIdx.x * blockDim.x + threadIdx.x;
    if (i < N) {
        float d = rsqrtf((float)deg[i] + 1.0f);
        dinv[i] = d;
        xd[i] = x[i] * d;
    }
}

// ---- K3a: per-block partial sums of deg (SCAN_B elems per block) ----
__global__ void k_partial(const int* __restrict__ deg, int N, int* __restrict__ bsum) {
    __shared__ int lds[SCAN_T];
    int tid = threadIdx.x;
    int base = blockIdx.x * SCAN_B + tid * 4;
    int s = 0;
    #pragma unroll
    for (int c = 0; c < 4; ++c) { int i = base + c; if (i < N) s += deg[i]; }
    lds[tid] = s;
    __syncthreads();
    for (int st = SCAN_T / 2; st > 0; st >>= 1) {
        if (tid < st) lds[tid] += lds[tid + st];
        __syncthreads();
    }
    if (tid == 0) bsum[blockIdx.x] = lds[0];
}

// ---- K3b: single-block exclusive scan of block sums (NB <= 256) ----
__global__ void k_scan_off(const int* __restrict__ bsum, int NB, int* __restrict__ boff) {
    __shared__ int lds[SCAN_T];
    int tid = threadIdx.x;
    int v = (tid < NB) ? bsum[tid] : 0;
    lds[tid] = v;
    __syncthreads();
    for (int off = 1; off < SCAN_T; off <<= 1) {
        int val = (tid >= off) ? lds[tid - off] : 0;
        __syncthreads();
        lds[tid] += val;
        __syncthreads();
    }
    if (tid < NB) boff[tid] = lds[tid] - v;   // exclusive
}

// ---- K3c: per-block exclusive scan + offset -> rowptr, cursor ----
__global__ void k_rowptr(const int* __restrict__ deg, int N, int E,
                         const int* __restrict__ boff,
                         int* __restrict__ rowptr, int* __restrict__ cursor) {
    __shared__ int lds[SCAN_T];
    int tid = threadIdx.x;
    int base = blockIdx.x * SCAN_B + tid * 4;
    int d[4];
    int ts = 0;
    #pragma unroll
    for (int c = 0; c < 4; ++c) { int i = base + c; d[c] = (i < N) ? deg[i] : 0; ts += d[c]; }
    lds[tid] = ts;
    __syncthreads();
    for (int off = 1; off < SCAN_T; off <<= 1) {
        int val = (tid >= off) ? lds[tid - off] : 0;
        __syncthreads();
        lds[tid] += val;
        __syncthreads();
    }
    int ex = lds[tid] - ts + boff[blockIdx.x];
    #pragma unroll
    for (int c = 0; c < 4; ++c) {
        int i = base + c;
        if (i < N) { rowptr[i] = ex; cursor[i] = ex; }
        ex += d[c];
    }
    if (blockIdx.x == 0 && tid == 0) rowptr[N] = E;
}

// ---- K4: counting-sort scatter: srcs sorted by dst ----
__global__ void k_csr_scatter(const int* __restrict__ ei, int E,
                              int* __restrict__ cursor, int* __restrict__ srcs) {
    int e = blockIdx.x * blockDim.x + threadIdx.x;
    if (e < E) {
        int u = ei[e];
        int v = ei[E + e];
        int pos = atomicAdd(&cursor[v], 1);
        srcs[pos] = u;
    }
}

// ---- K5: layer-1 gather: stot[v] = dinv[v]*(sum_in xd[u] + xd[v]) ----
__global__ void k_s_gather(const int* __restrict__ rowptr, const int* __restrict__ srcs,
                           const float* __restrict__ xd, const float* __restrict__ dinv,
                           float* __restrict__ stot, int N) {
    int v = blockIdx.x * blockDim.x + threadIdx.x;
    if (v < N) {
        int beg = rowptr[v], end = rowptr[v + 1];
        float s = xd[v];                       // self-loop
        for (int k = beg; k < end; ++k) s += xd[srcs[k]];
        stot[v] = dinv[v] * s;
    }
}

// ---- K6: Pd[v,:] = dinv[v] * (relu(stot[v]*W1 + b1) @ Wcomb)  [N,32] ----
// 8 threads per node, 4 channels each (float4)
__global__ void k_P(const float* __restrict__ stot, const float* __restrict__ dinv,
                    const float* __restrict__ W1, const float* __restrict__ b1,
                    const float* __restrict__ Wc, float* __restrict__ Pd, int N) {
    int t = blockIdx.x * blockDim.x + threadIdx.x;
    int v = t >> 3, g = t & 7;
    if (v < N) {
        float st = stot[v], di = dinv[v];
        const float4* WcV = (const float4*)Wc;   // row j = 8 float4s
        float4 acc = make_float4(0.f, 0.f, 0.f, 0.f);
        #pragma unroll 8
        for (int j = 0; j < HID; ++j) {
            float h = st * W1[j] + b1[j];
            h = h > 0.f ? h : 0.f;
            float4 w = WcV[j * 8 + g];
            acc.x += h * w.x; acc.y += h * w.y; acc.z += h * w.z; acc.w += h * w.w;
        }
        float4* PdV = (float4*)Pd;
        acc.x *= di; acc.y *= di; acc.z *= di; acc.w *= di;
        PdV[v * 8 + g] = acc;
    }
}

// ---- K7: layer-2 gather: out[v,o] = bc[o] + dinv[v]*(Pd[v,o] + sum_in Pd[u,o]) ----
// 32 lanes per node (one channel each)
__global__ void k_out_gather(const int* __restrict__ rowptr, const int* __restrict__ srcs,
                             const float* __restrict__ Pd, const float* __restrict__ dinv,
                             const float* __restrict__ bc, float* __restrict__ out, int N) {
    int t = blockIdx.x * blockDim.x + threadIdx.x;
    int v = t >> 5, o = t & 31;
    if (v < N) {
        int beg = rowptr[v], end = rowptr[v + 1];
        float acc = Pd[v * OUTC + o];          // self-loop (dinv[v] applied at end)
        for (int k = beg; k < end; ++k) {
            int u = srcs[k];                   // broadcast across the 32 lanes
            acc += Pd[u * OUTC + o];
        }
        out[v * OUTC + o] = bc[o] + dinv[v] * acc;
    }
}

extern "C" void kernel_launch(void* const* d_in, const int* in_sizes, int n_in,
                              void* d_out, int out_size, void* d_ws, size_t ws_size,
                              hipStream_t stream) {
    const float* x   = (const float*)d_in[0];
    const int*   ei  = (const int*)d_in[1];   // [2,E] int32: row0=src, row1=dst
    const float* W1  = (const float*)d_in[2];
    const float* b1  = (const float*)d_in[3];
    const float* W2  = (const float*)d_in[4];
    const float* b2  = (const float*)d_in[5];
    const float* Wfc = (const float*)d_in[6];
    const float* bfc = (const float*)d_in[7];
    float* out = (float*)d_out;

    const int N = in_sizes[0];
    const int E = in_sizes[1] / 2;
    const int NB = (N + SCAN_B - 1) / SCAN_B;  // <= 256 for N <= 262144

    // workspace layout (4-byte words): ~38N + E + 4.7k words (~21.8 MB)
    int* deg    = (int*)d_ws;                  // N
    int* rowptr = deg + N;                     // N+1
    int* cursor = rowptr + (N + 1);            // N
    int* srcs   = cursor + N;                  // E
    int* bsum   = srcs + E;                    // <=256
    int* boff   = bsum + 256;                  // <=256
    float* dinv = (float*)(boff + 256);        // N
    float* xd   = dinv + N;                    // N
    float* stot = xd + N;                      // N
    float* Pd   = stot + N;                    // N*OUTC
    float* Wc   = Pd + (size_t)N * OUTC;       // HID*OUTC
    float* bc   = Wc + HID * OUTC;             // OUTC

    hipMemsetAsync(deg, 0, (size_t)N * sizeof(int), stream);

    k_wcomb<<<(HID * OUTC + 255) / 256, 256, 0, stream>>>(W2, Wfc, b2, bfc, Wc, bc);
    k_deg<<<(E + 255) / 256, 256, 0, stream>>>(ei + E, E, deg);
    k_dinv<<<(N + 255) / 256, 256, 0, stream>>>(deg, x, dinv, xd, N);
    k_partial<<<NB, SCAN_T, 0, stream>>>(deg, N, bsum);
    k_scan_off<<<1, SCAN_T, 0, stream>>>(bsum, NB, boff);
    k_rowptr<<<NB, SCAN_T, 0, stream>>>(deg, N, E, boff, rowptr, cursor);
    k_csr_scatter<<<(E + 255) / 256, 256, 0, stream>>>(ei, E, cursor, srcs);
    k_s_gather<<<(N + 255) / 256, 256, 0, stream>>>(rowptr, srcs, xd, dinv, stot, N);
    k_P<<<(N * 8 + 255) / 256, 256, 0, stream>>>(stot, dinv, W1, b1, Wc, Pd, N);
    {
        long long threads = (long long)N * OUTC;
        int blocks = (int)((threads + 255) / 256);
        k_out_gather<<<blocks, 256, 0, stream>>>(rowptr, srcs, Pd, dinv, bc, out, N);
    }
}